// Round 14
// baseline (1011.262 us; speedup 1.0000x reference)
//
#include <hip/hip_runtime.h>
#include <math.h>
#include <float.h>

#define INPUT_DIM 1024
#define HIDDEN 128
#define KSEL 10
#define KC 12                 // candidates per side (containment margin 2)

// scores kernel geometry: ONE wave per block, 16 rows x 256 pc, no barriers.
#define WROWS 16
#define BK 64
#define KT (INPUT_DIM / BK)   // 16
#define NSEL1 32              // stage-1 chunks per bag

typedef short short8 __attribute__((ext_vector_type(8)));
typedef float f32x4 __attribute__((ext_vector_type(4)));

static __device__ __forceinline__ unsigned short f2bf(float f) {
    union { float f; unsigned u; } v; v.f = f;
    unsigned r = v.u + 0x7FFF + ((v.u >> 16) & 1);   // RNE
    return (unsigned short)(r >> 16);
}
static __device__ __forceinline__ float fast_tanh(float a) {
    float e = __expf(2.0f * a);
    return 1.0f - 2.0f / (e + 1.0f);
}
static __device__ __forceinline__ float fast_sigmoid(float a) {
    return 1.0f / (1.0f + __expf(-a));
}

// ---------------------------------------------------------------------------
// Repack W into MFMA B-fragment order (16x16x32), bf16 RNE (exact rescore
// of the candidate set absorbs the approx error).
// pc = 2h + (0 Wv, 1 Wu). wp[kg][cg][lane][e]: k = kg*32+(lane>>4)*8+e,
// pc = cg*16+(lane&15). grid 512 (= 32 kg x 16 cg) x 64.
// ---------------------------------------------------------------------------
__global__ __launch_bounds__(64) void repack_kernel(
    const float* __restrict__ Wv, const float* __restrict__ Wu,
    unsigned short* __restrict__ wp_hi)
{
    int bid = blockIdx.x;           // kg*16 + cg
    int l = threadIdx.x;
    int pc = (bid & 15) * 16 + (l & 15);
    int h = pc >> 1;
    const float* src = (pc & 1) ? Wu : Wv;
    int kbase = (bid >> 4) * 32 + (l >> 4) * 8;
    size_t off = ((size_t)bid * 64 + l) * 8;
    #pragma unroll
    for (int e = 0; e < 8; ++e)
        wp_hi[off + e] = f2bf(src[(size_t)(kbase + e) * HIDDEN + h]);
}

// ---------------------------------------------------------------------------
// Kernel 1: approx scores, single bf16 MFMA term, ZERO-BARRIER design.
// Each 64-thread block = 1 wave owning 16 rows x all 256 pc:
//  - wave-private LDS double buffer (2 x 2 KB) -> ds ordering is the wave's
//    own in-order DS pipe; NO s_barrier in the whole main loop.
//  - x register-staged: 4 dwordx4/lane, 8 cvt_pk, 2 ds_write_b128; loads for
//    tile kt+3 issued at the END of step kt (newest in vmcnt FIFO) and
//    consumed 2 steps later as the OLDEST -> every wait is counted, no
//    forced drains (round-9 FIFO discipline, now per-wave).
//  - B streamed from L2 in quads, double-buffered (bq0/bq1).
//  - acc = 16 n-frags (64 VGPR); 12 independent waves/CU hide all latency.
// XOR swizzle (chunk ^ row&7) keeps LDS reads ~2-way (free).
// ---------------------------------------------------------------------------
__global__ __launch_bounds__(64) void scores_kernel(
    const float* __restrict__ x, const unsigned short* __restrict__ wp,
    const float* __restrict__ bv, const float* __restrict__ bu,
    const float* __restrict__ Ww, const float* __restrict__ bw,
    float* __restrict__ scores, float* __restrict__ atten, int N)
{
    __shared__ __align__(16) unsigned short xs[2][WROWS * BK];  // 4 KB total

    const int l = threadIdx.x;
    const int b = blockIdx.y;
    const int i0 = blockIdx.x * WROWS;
    const float* xb = x + (size_t)b * N * INPUT_DIM;

    // staging: lane l -> row l>>2, fp32 cols (l&3)*16 .. +15 (contiguous 16)
    const int srow = l >> 2;
    const float* gp = xb + (size_t)min(i0 + srow, N - 1) * INPUT_DIM + (l & 3) * 16;
    const int wb0 = srow * BK + (((2 * (l & 3))     ^ (srow & 7)) * 8);
    const int wb1 = srow * BK + (((2 * (l & 3) + 1) ^ (srow & 7)) * 8);

    f32x4 acc[16];
    #pragma unroll
    for (int n = 0; n < 16; ++n) acc[n] = (f32x4){0.f, 0.f, 0.f, 0.f};

    float4 xa[4], xc[4];
    short8 q0[4], q1[4];

#define XLOAD(X, T) do { \
        const float* _p = gp + (size_t)min((T), KT - 1) * BK; \
        X[0] = *(const float4*)(_p); \
        X[1] = *(const float4*)(_p + 4); \
        X[2] = *(const float4*)(_p + 8); \
        X[3] = *(const float4*)(_p + 12); \
    } while (0)

#define XWRITE(X, SLOT) do { \
        unsigned u0, u1, u2, u3, u4, u5, u6, u7; \
        asm("v_cvt_pk_bf16_f32 %0, %1, %2" : "=v"(u0) : "v"(X[0].x), "v"(X[0].y)); \
        asm("v_cvt_pk_bf16_f32 %0, %1, %2" : "=v"(u1) : "v"(X[0].z), "v"(X[0].w)); \
        asm("v_cvt_pk_bf16_f32 %0, %1, %2" : "=v"(u2) : "v"(X[1].x), "v"(X[1].y)); \
        asm("v_cvt_pk_bf16_f32 %0, %1, %2" : "=v"(u3) : "v"(X[1].z), "v"(X[1].w)); \
        asm("v_cvt_pk_bf16_f32 %0, %1, %2" : "=v"(u4) : "v"(X[2].x), "v"(X[2].y)); \
        asm("v_cvt_pk_bf16_f32 %0, %1, %2" : "=v"(u5) : "v"(X[2].z), "v"(X[2].w)); \
        asm("v_cvt_pk_bf16_f32 %0, %1, %2" : "=v"(u6) : "v"(X[3].x), "v"(X[3].y)); \
        asm("v_cvt_pk_bf16_f32 %0, %1, %2" : "=v"(u7) : "v"(X[3].z), "v"(X[3].w)); \
        *(uint4*)(&xs[(SLOT)][wb0]) = make_uint4(u0, u1, u2, u3); \
        *(uint4*)(&xs[(SLOT)][wb1]) = make_uint4(u4, u5, u6, u7); \
    } while (0)

#define AREAD(DST, SLOT, KS) \
        DST = *(const short8*)(&xs[(SLOT)][(l & 15) * BK + ((((KS) * 4 + (l >> 4)) ^ (l & 7)) * 8)])

#define BLOADG(Q, KT_, G) do { \
        const unsigned _kg = (unsigned)((KT_) * 2 + ((G) >> 2)); \
        const unsigned _nb = ((G) & 3) * 4; \
        _Pragma("unroll") \
        for (int j = 0; j < 4; ++j) \
            Q[j] = *(const short8*)(wp + (((_kg * 16 + _nb + j) * 64 + l) * 8)); \
    } while (0)

#define MFMAG(Q, A, G) do { \
        const int _nb = ((G) & 3) * 4; \
        _Pragma("unroll") \
        for (int j = 0; j < 4; ++j) \
            acc[_nb + j] = __builtin_amdgcn_mfma_f32_16x16x32_bf16(A, Q[j], acc[_nb + j], 0, 0, 0); \
    } while (0)

#define BODY(KT_, XSET) do { \
        const int _slot = (KT_) & 1; \
        short8 a0, a1; \
        AREAD(a0, _slot, 0); \
        AREAD(a1, _slot, 1); \
        XWRITE(XSET, _slot ^ 1);          /* tile KT_+1 into other slot */ \
        asm volatile("" ::: "memory"); \
        __builtin_amdgcn_s_setprio(1); \
        BLOADG(q0, KT_, 0); \
        BLOADG(q1, KT_, 1); MFMAG(q0, a0, 0); \
        BLOADG(q0, KT_, 2); MFMAG(q1, a0, 1); \
        BLOADG(q1, KT_, 3); MFMAG(q0, a0, 2); \
        BLOADG(q0, KT_, 4); MFMAG(q1, a0, 3); \
        BLOADG(q1, KT_, 5); MFMAG(q0, a1, 4); \
        BLOADG(q0, KT_, 6); MFMAG(q1, a1, 5); \
        BLOADG(q1, KT_, 7); MFMAG(q0, a1, 6); \
        MFMAG(q1, a1, 7); \
        __builtin_amdgcn_s_setprio(0); \
        __builtin_amdgcn_sched_barrier(0); \
        XLOAD(XSET, (KT_) + 3);           /* newest in FIFO, 2-kt flight */ \
        asm volatile("" ::: "memory"); \
    } while (0)

    // prologue: tile0 -> slot0 (one-time vmcnt stall); tiles 1,2 in flight
    XLOAD(xa, 0);
    XWRITE(xa, 0);
    XLOAD(xa, 1);
    XLOAD(xc, 2);
    asm volatile("" ::: "memory");

    for (int kt2 = 0; kt2 < KT / 2; ++kt2) {
        BODY(2 * kt2,     xa);
        BODY(2 * kt2 + 1, xc);
    }

#undef XLOAD
#undef XWRITE
#undef AREAD
#undef BLOADG
#undef MFMAG
#undef BODY

    // ---- epilogue: gate, project, in-wave row-reduce (no LDS, no barrier) ----
    const bool isV = ((l & 1) == 0);
    float cs[4] = {0.f, 0.f, 0.f, 0.f};
    #pragma unroll
    for (int n = 0; n < 16; ++n) {
        int h = (n * 16 + (l & 15)) >> 1;
        float bvv = bv[h], buu = bu[h], www = Ww[h];
        #pragma unroll
        for (int r = 0; r < 4; ++r) {
            float v = acc[n][r];
            float u = __shfl_xor(v, 1, 64);     // partner col (U pre-act)
            if (isV)
                cs[r] += fast_tanh(v + bvv) * fast_sigmoid(u + buu) * www;
        }
    }
    #pragma unroll
    for (int r = 0; r < 4; ++r)
        #pragma unroll
        for (int off = 1; off < 16; off <<= 1)
            cs[r] += __shfl_xor(cs[r], off, 64);

    if ((l & 15) == 0) {
        float bw0 = bw[0];
        #pragma unroll
        for (int r = 0; r < 4; ++r) {
            int gi = i0 + (l >> 4) * 4 + r;     // C/D: row = (lane>>4)*4 + reg
            if (gi < N) {
                scores[(size_t)b * N + gi] = cs[r] + bw0;
                atten[(size_t)b * N + gi] = 0.0f;
            }
        }
    }
}

// ---------------------------------------------------------------------------
// Kernel 2a: per (chunk, bag) approx top-12 / bottom-12. 1 wave per block.
// ---------------------------------------------------------------------------
__global__ __launch_bounds__(64) void select1_kernel(
    const float* __restrict__ scores, float* __restrict__ cv, int* __restrict__ ci,
    int N, int CH)
{
    const int r = blockIdx.x, b = blockIdx.y;
    const int tid = threadIdx.x;
    const float* s = scores + (size_t)b * N;
    const int start = r * CH;
    const int end = min(N, start + CH);

    float tv[KC]; int ti[KC];
    float lv[KC]; int li[KC];
    #pragma unroll
    for (int j = 0; j < KC; ++j) { tv[j] = -FLT_MAX; ti[j] = -1; lv[j] = FLT_MAX; li[j] = -1; }

    for (int i = start + tid; i < end; i += 64) {
        float v = s[i];
        if (v > tv[KC-1]) {
            #pragma unroll
            for (int j = KC-1; j >= 1; --j) {
                if (v > tv[j-1])      { tv[j] = tv[j-1]; ti[j] = ti[j-1]; }
                else if (v > tv[j])   { tv[j] = v;       ti[j] = i;       }
            }
            if (v > tv[0]) { tv[0] = v; ti[0] = i; }
        }
        if (v < lv[KC-1]) {
            #pragma unroll
            for (int j = KC-1; j >= 1; --j) {
                if (v < lv[j-1])      { lv[j] = lv[j-1]; li[j] = li[j-1]; }
                else if (v < lv[j])   { lv[j] = v;       li[j] = i;       }
            }
            if (v < lv[0]) { lv[0] = v; li[0] = i; }
        }
    }

    size_t base = ((size_t)b * NSEL1 + r) * 2 * KC;
    for (int rd = 0; rd < KC; ++rd) {
        float v = tv[0]; int who = tid;
        #pragma unroll
        for (int off = 32; off > 0; off >>= 1) {
            float ov = __shfl_down(v, off, 64);
            int ow = __shfl_down(who, off, 64);
            if (ov > v) { v = ov; who = ow; }
        }
        int bwho = __shfl(who, 0, 64);
        if (tid == bwho) {
            cv[base + rd] = tv[0]; ci[base + rd] = ti[0];
            #pragma unroll
            for (int j = 0; j < KC-1; ++j) { tv[j] = tv[j+1]; ti[j] = ti[j+1]; }
            tv[KC-1] = -FLT_MAX;
        }
    }
    for (int rd = 0; rd < KC; ++rd) {
        float v = lv[0]; int who = tid;
        #pragma unroll
        for (int off = 32; off > 0; off >>= 1) {
            float ov = __shfl_down(v, off, 64);
            int ow = __shfl_down(who, off, 64);
            if (ov < v) { v = ov; who = ow; }
        }
        int bwho = __shfl(who, 0, 64);
        if (tid == bwho) {
            cv[base + KC + rd] = lv[0]; ci[base + KC + rd] = li[0];
            #pragma unroll
            for (int j = 0; j < KC-1; ++j) { lv[j] = lv[j+1]; li[j] = li[j+1]; }
            lv[KC-1] = FLT_MAX;
        }
    }
}

// ---------------------------------------------------------------------------
// Kernel 2b: per bag, merge -> global approx top-12/bottom-12 indices.
// ---------------------------------------------------------------------------
__global__ __launch_bounds__(64) void select2_kernel(
    const float* __restrict__ cv, const int* __restrict__ ci,
    int* __restrict__ cand_idx)
{
    const int b = blockIdx.x;
    const int tid = threadIdx.x;

    float tv[KC]; int ti[KC];
    float lv[KC]; int li[KC];
    #pragma unroll
    for (int j = 0; j < KC; ++j) { tv[j] = -FLT_MAX; ti[j] = -1; lv[j] = FLT_MAX; li[j] = -1; }

    for (int c = tid; c < NSEL1 * KC; c += 64) {
        int rr = c / KC, jj = c % KC;
        size_t base = ((size_t)b * NSEL1 + rr) * 2 * KC;
        {
            float v = cv[base + jj]; int idx = ci[base + jj];
            if (v > tv[KC-1]) {
                #pragma unroll
                for (int j = KC-1; j >= 1; --j) {
                    if (v > tv[j-1])      { tv[j] = tv[j-1]; ti[j] = ti[j-1]; }
                    else if (v > tv[j])   { tv[j] = v;       ti[j] = idx;     }
                }
                if (v > tv[0]) { tv[0] = v; ti[0] = idx; }
            }
        }
        {
            float v = cv[base + KC + jj]; int idx = ci[base + KC + jj];
            if (v < lv[KC-1]) {
                #pragma unroll
                for (int j = KC-1; j >= 1; --j) {
                    if (v < lv[j-1])      { lv[j] = lv[j-1]; li[j] = li[j-1]; }
                    else if (v < lv[j])   { lv[j] = v;       li[j] = idx;     }
                }
                if (v < lv[0]) { lv[0] = v; li[0] = idx; }
            }
        }
    }

    for (int rd = 0; rd < KC; ++rd) {
        float v = tv[0]; int who = tid;
        #pragma unroll
        for (int off = 32; off > 0; off >>= 1) {
            float ov = __shfl_down(v, off, 64);
            int ow = __shfl_down(who, off, 64);
            if (ov > v) { v = ov; who = ow; }
        }
        int bwho = __shfl(who, 0, 64);
        if (tid == bwho) {
            cand_idx[b * 2 * KC + rd] = ti[0];
            #pragma unroll
            for (int j = 0; j < KC-1; ++j) { tv[j] = tv[j+1]; ti[j] = ti[j+1]; }
            tv[KC-1] = -FLT_MAX;
        }
    }
    for (int rd = 0; rd < KC; ++rd) {
        float v = lv[0]; int who = tid;
        #pragma unroll
        for (int off = 32; off > 0; off >>= 1) {
            float ov = __shfl_down(v, off, 64);
            int ow = __shfl_down(who, off, 64);
            if (ov < v) { v = ov; who = ow; }
        }
        int bwho = __shfl(who, 0, 64);
        if (tid == bwho) {
            cand_idx[b * 2 * KC + KC + rd] = li[0];
            #pragma unroll
            for (int j = 0; j < KC-1; ++j) { lv[j] = lv[j+1]; li[j] = li[j+1]; }
            lv[KC-1] = FLT_MAX;
        }
    }
}

// ---------------------------------------------------------------------------
// Kernel 3: exact fp32 rescore of each candidate row.
// ---------------------------------------------------------------------------
__global__ __launch_bounds__(256) void rescore_kernel(
    const float* __restrict__ x,
    const float* __restrict__ Wv, const float* __restrict__ bv,
    const float* __restrict__ Wu, const float* __restrict__ bu,
    const float* __restrict__ Ww, const float* __restrict__ bw,
    const int* __restrict__ cand_idx, float* __restrict__ cand_score, int N)
{
    const int j = blockIdx.x, b = blockIdx.y;
    const int tid = threadIdx.x;
    __shared__ float xsr[INPUT_DIM];
    __shared__ float sp[4];

    int idx = cand_idx[b * 2 * KC + j];
    const float* xr = x + ((size_t)b * N + idx) * INPUT_DIM;
    *(float4*)(&xsr[tid * 4]) = *(const float4*)(&xr[tid * 4]);
    __syncthreads();

    const int h = tid >> 1;
    const int isU = tid & 1;
    const float* W = isU ? Wu : Wv;
    float s = 0.f;
    #pragma unroll 8
    for (int k = 0; k < INPUT_DIM; ++k)
        s = fmaf(xsr[k], W[(size_t)k * HIDDEN + h], s);

    float other = __shfl_xor(s, 1, 64);
    float g = 0.f;
    if (!isU) {
        float vv = tanhf(s + bv[h]);
        float uu = 1.0f / (1.0f + expf(-(other + bu[h])));
        g = vv * uu * Ww[h];
    }
    #pragma unroll
    for (int off = 1; off < 64; off <<= 1) g += __shfl_xor(g, off, 64);
    if ((tid & 63) == 0) sp[tid >> 6] = g;
    __syncthreads();
    if (tid == 0)
        cand_score[b * 2 * KC + j] = sp[0] + sp[1] + sp[2] + sp[3] + bw[0];
}

// ---------------------------------------------------------------------------
// Kernel 4: exact top/bottom-10 sets, exact softmax, scatter atten, gather Z.
// ---------------------------------------------------------------------------
__global__ __launch_bounds__(256) void final_kernel(
    const float* __restrict__ x, const int* __restrict__ cand_idx,
    const float* __restrict__ cand_score,
    float* __restrict__ atten, float* __restrict__ Z, int N)
{
    const int b = blockIdx.x;
    const int tid = threadIdx.x;
    __shared__ int fidx[2 * KSEL];
    __shared__ float fw[2 * KSEL];

    if (tid == 0) {
        float cs[2 * KC]; int ciX[2 * KC]; bool used[2 * KC];
        #pragma unroll
        for (int j2 = 0; j2 < 2 * KC; ++j2) {
            cs[j2] = cand_score[b * 2 * KC + j2];
            ciX[j2] = cand_idx[b * 2 * KC + j2];
            used[j2] = false;
        }
        float fs[2 * KSEL];
        for (int r = 0; r < KSEL; ++r) {
            int best = -1; float bvv = -FLT_MAX;
            for (int j2 = 0; j2 < KC; ++j2)
                if (!used[j2] && cs[j2] > bvv) { bvv = cs[j2]; best = j2; }
            used[best] = true; fidx[r] = ciX[best]; fs[r] = bvv;
        }
        for (int r = 0; r < KSEL; ++r) {
            int best = -1; float bvv = FLT_MAX;
            for (int j2 = KC; j2 < 2 * KC; ++j2)
                if (!used[j2] && cs[j2] < bvv) { bvv = cs[j2]; best = j2; }
            used[best] = true; fidx[KSEL + r] = ciX[best]; fs[KSEL + r] = bvv;
        }
        float m = -FLT_MAX;
        for (int j2 = 0; j2 < 2 * KSEL; ++j2) m = fmaxf(m, fs[j2]);
        float e[2 * KSEL], sum = 0.f;
        for (int j2 = 0; j2 < 2 * KSEL; ++j2) { e[j2] = expf(fs[j2] - m); sum += e[j2]; }
        float inv = 1.0f / sum;
        for (int j2 = 0; j2 < 2 * KSEL; ++j2) {
            fw[j2] = e[j2] * inv;
            atten[(size_t)b * N + fidx[j2]] = fw[j2];
        }
    }
    __syncthreads();

    float4 acc = make_float4(0.f, 0.f, 0.f, 0.f);
    #pragma unroll
    for (int j2 = 0; j2 < 2 * KSEL; ++j2) {
        int idx = fidx[j2];
        float wgt = fw[j2];
        const float4* xr = (const float4*)(x + ((size_t)b * N + idx) * INPUT_DIM);
        float4 v = xr[tid];
        acc.x = fmaf(wgt, v.x, acc.x);
        acc.y = fmaf(wgt, v.y, acc.y);
        acc.z = fmaf(wgt, v.z, acc.z);
        acc.w = fmaf(wgt, v.w, acc.w);
    }
    ((float4*)(Z + (size_t)b * INPUT_DIM))[tid] = acc;
}

extern "C" void kernel_launch(void* const* d_in, const int* in_sizes, int n_in,
                              void* d_out, int out_size, void* d_ws, size_t ws_size,
                              hipStream_t stream)
{
    const float* x  = (const float*)d_in[0];
    const float* Wv = (const float*)d_in[1];
    const float* bv = (const float*)d_in[2];
    const float* Wu = (const float*)d_in[3];
    const float* bu = (const float*)d_in[4];
    const float* Ww = (const float*)d_in[5];
    const float* bw = (const float*)d_in[6];

    const int B = 8;
    const int N = in_sizes[0] / (B * INPUT_DIM);   // 50000

    float* Z = (float*)d_out;                              // [B,1024]
    float* atten = (float*)d_out + (size_t)B * INPUT_DIM;  // [B,N]

    // workspace layout
    char* p = (char*)d_ws;
    float* scores = (float*)p;                  p += (size_t)B * N * sizeof(float);
    unsigned short* wp = (unsigned short*)p;    p += (size_t)INPUT_DIM * 256 * sizeof(unsigned short);
    float* cand_v = (float*)p;                  p += (size_t)B * NSEL1 * 2 * KC * sizeof(float);
    int* cand_i = (int*)p;                      p += (size_t)B * NSEL1 * 2 * KC * sizeof(int);
    int* cand_idx = (int*)p;                    p += (size_t)B * 2 * KC * sizeof(int);
    float* cand_score = (float*)p;

    repack_kernel<<<512, 64, 0, stream>>>(Wv, Wu, wp);

    dim3 g1((N + WROWS - 1) / WROWS, B);
    scores_kernel<<<g1, 64, 0, stream>>>(x, wp, bv, bu, Ww, bw, scores, atten, N);

    int CH = (N + NSEL1 - 1) / NSEL1;
    dim3 g2(NSEL1, B);
    select1_kernel<<<g2, 64, 0, stream>>>(scores, cand_v, cand_i, N, CH);
    select2_kernel<<<B, 64, 0, stream>>>(cand_v, cand_i, cand_idx);

    dim3 g3(2 * KC, B);
    rescore_kernel<<<g3, 256, 0, stream>>>(x, Wv, bv, Wu, bu, Ww, bw, cand_idx, cand_score, N);
    final_kernel<<<B, 256, 0, stream>>>(x, cand_idx, cand_score, atten, Z, N);
}